// Round 5
// baseline (279.890 us; speedup 1.0000x reference)
//
#include <hip/hip_runtime.h>

// Problem constants (x: (512, 9, 84, 84) f32)
#define N_ELEM   7056        // 84*84
#define DIM      84
#define M_STEPS  14111       // 2*N_ELEM - 1
#define N_ROWS   4608        // 512*9
#define NCHUNK   384
#define KSTEPS   37          // 384*37 = 14208 >= 14111 (tail chunks empty -> identity)
#define WINW     208         // window: (K-1)+2*84+1 = 205, padded to 208 (416 B = 26 uint4)
#define TPB      256
#define NJV      1764        // N_ELEM / 4
#define GR       9           // rows (one image) per gather block -> 512 blocks

typedef float f4 __attribute__((ext_vector_type(4)));

// ---- JAX threefry2x32 block cipher (20 rounds), bit-exact port ----
__device__ __forceinline__ void threefry2x32(unsigned k0, unsigned k1,
                                             unsigned x0, unsigned x1,
                                             unsigned &o0, unsigned &o1) {
  const unsigned ks0 = k0, ks1 = k1, ks2 = k0 ^ k1 ^ 0x1BD11BDAu;
  x0 += ks0; x1 += ks1;
#define ROTL(x, r) (((x) << (r)) | ((x) >> (32 - (r))))
#define RND(r) { x0 += x1; x1 = ROTL(x1, r); x1 ^= x0; }
  RND(13) RND(15) RND(26) RND(6)
  x0 += ks1; x1 += ks2 + 1u;
  RND(17) RND(29) RND(16) RND(24)
  x0 += ks2; x1 += ks0 + 2u;
  RND(13) RND(15) RND(26) RND(6)
  x0 += ks0; x1 += ks1 + 3u;
  RND(17) RND(29) RND(16) RND(24)
  x0 += ks1; x1 += ks2 + 4u;
  RND(13) RND(15) RND(26) RND(6)
  x0 += ks2; x1 += ks0 + 5u;
  o0 = x0; o1 = x1;
#undef RND
#undef ROTL
}

// jax.random.choice(key,5,p=[.55,.1125,.1125,.1125,.1125]) — searchsorted on f32
// cumsum (sequential f32 cumsum verified exact-arithmetic: q4 == 1.0f exactly).
// Partitionable-threefry bits: b1 ^ b2 with counter (0, t).
__device__ __forceinline__ int r_from_bits(unsigned bits) {
  const float p8 = 0.1125f;
  const float q0 = 0.55f;
  const float q1 = q0 + p8;
  const float q2 = q1 + p8;
  const float q3 = q2 + p8;
  const float q4 = q3 + p8;
  float u  = __uint_as_float((bits >> 9) | 0x3F800000u) - 1.0f; // [0,1)
  float rv = q4 * (1.0f - u);
  return (int)(q0 < rv) + (int)(q1 < rv) + (int)(q2 < rv) + (int)(q3 < rv);
}

// Window bounds for chunk c: steps t in [t0,t1); touched positions are within
// [imin-DIM, imax+DIM] clamped to [0, N_ELEM-1], where i(t) = |t - (N_ELEM-1)|.
// t0 clamped so tail chunks past M_STEPS become empty (identity windows).
__device__ __forceinline__ void chunk_bounds(int c, int &t0, int &t1, int &lo, int &hi) {
  t0 = c * KSTEPS; if (t0 > M_STEPS) t0 = M_STEPS;
  t1 = t0 + KSTEPS; if (t1 > M_STEPS) t1 = M_STEPS;
  int a0 = t0 - (N_ELEM - 1);       if (a0 < 0) a0 = -a0;
  int a1 = (t1 - 1) - (N_ELEM - 1); if (a1 < 0) a1 = -a1;
  int imax = a0 > a1 ? a0 : a1;
  int imin;
  if (t0 <= N_ELEM - 1 && t1 - 1 >= N_ELEM - 1) imin = 0;
  else imin = a0 < a1 ? a0 : a1;
  lo = imin - DIM; if (lo < 0) lo = 0;
  hi = imax + DIM; if (hi > N_ELEM - 1) hi = N_ELEM - 1;
}

// Kernel 1: one block per chunk (chunks independent, each starts from identity).
// Parallel threefry for the chunk's draws, then lane 0 runs the <=37 sequential
// swaps in a private LDS window; window written to global ws (26 uint4).
__global__ __launch_bounds__(TPB) void chunk_kernel(unsigned* __restrict__ winG) {
  __shared__ __align__(16) unsigned short w[WINW];
  __shared__ unsigned char rs[KSTEPS + 3];

  const int c = blockIdx.x, tid = threadIdx.x;
  int t0, t1, lo, hi; chunk_bounds(c, t0, t1, lo, hi);
  const int nt = t1 - t0;

  if (tid < WINW) w[tid] = (unsigned short)(lo + tid);   // pad entries unused
  if (tid < nt) {
    unsigned y0, y1;
    threefry2x32(0u, 42u, 0u, (unsigned)(t0 + tid), y0, y1);
    rs[tid] = (unsigned char)r_from_bits(y0 ^ y1);
  }
  __syncthreads();

  if (tid == 0) {
    for (int k = 0; k < nt; ++k) {
      int t = t0 + k;
      int i = t - (N_ELEM - 1); if (i < 0) i = -i;
      int r = rs[k];
      int off = (r == 1) ? 1 : (r == 2) ? -1 : (r == 3) ? DIM : (r == 4) ? -DIM : 0;
      int idx = i + off;
      bool doit = (r != 0) && (idx > 0) && (idx < N_ELEM);
      int je = doit ? idx : i;              // branchless self-swap when !doit
      unsigned short a = w[i  - lo];
      unsigned short b = w[je - lo];
      w[i  - lo] = b;
      w[je - lo] = a;
    }
  }
  __syncthreads();

  const uint4* w4 = (const uint4*)w;
  if (tid < WINW * 2 / 16) ((uint4*)winG)[c * (WINW * 2 / 16) + tid] = w4[tid];
}

// Kernel 2: compose. 3 passes of 128 windows (53 KB LDS each); each of 28
// blocks traces 252 indices backward through chunks c = 383..0.
#define TRACE_BLOCKS 28        // 28 * 252 = 7056
#define WPP 128                // windows per pass
__global__ __launch_bounds__(TPB) void trace_kernel(const unsigned* __restrict__ winG,
                                                    int* __restrict__ permG) {
  __shared__ __align__(16) unsigned short w[WPP * WINW];  // 53248 B
  const int tid = threadIdx.x;
  const int U4_PER_WIN = WINW * 2 / 16;                   // 26

  int y = blockIdx.x * 252 + tid;                         // traced index (tid<252)

  for (int pass = NCHUNK / WPP - 1; pass >= 0; --pass) {
    const int cbase = pass * WPP;
    uint4* w4 = (uint4*)w;
    const uint4* g4 = (const uint4*)winG + cbase * U4_PER_WIN;
    for (int k = tid; k < WPP * U4_PER_WIN; k += TPB) w4[k] = g4[k];
    __syncthreads();

    if (tid < 252) {
      for (int c = WPP - 1; c >= 0; --c) {
        int t0, t1, lo, hi; chunk_bounds(cbase + c, t0, t1, lo, hi);
        unsigned e = (unsigned)(y - lo);
        if (e <= (unsigned)(hi - lo)) y = (int)w[c * WINW + e];
      }
    }
    __syncthreads();   // before next pass overwrites LDS
  }

  if (tid < 252) permG[blockIdx.x * 252 + tid] = y;
}

// Kernel 3: one block per 9-row image. perm cached ONCE in LDS as ushort
// (14 KB — removes the 130 MB/dispatch global perm re-read of the previous
// version), then pure streaming: per v, one ushort4 LDS read (4-way b64
// conflict ~ free) feeds 9 rows x (4 scattered dword reads + 1 coalesced
// nontemporal float4 store). Single barrier; 36 loads in flight per iter.
__global__ __launch_bounds__(TPB) void gather_kernel(const float* __restrict__ x,
                                                     const int* __restrict__ perm,
                                                     float* __restrict__ out) {
  __shared__ __align__(16) unsigned short p16[N_ELEM];    // 14112 B
  const int tid = threadIdx.x;

  const int4* pi4 = (const int4*)perm;
  for (int v = tid; v < NJV; v += TPB) {
    int4 p = pi4[v];
    ushort4 s;
    s.x = (unsigned short)p.x; s.y = (unsigned short)p.y;
    s.z = (unsigned short)p.z; s.w = (unsigned short)p.w;
    ((ushort4*)p16)[v] = s;
  }
  __syncthreads();

  const size_t base = (size_t)blockIdx.x * GR * N_ELEM;
  const float* xb = x + base;
  float*       ob = out + base;

  for (int v = tid; v < NJV; v += TPB) {
    ushort4 p = ((const ushort4*)p16)[v];
#pragma unroll
    for (int rr = 0; rr < GR; ++rr) {
      const float* xr = xb + rr * N_ELEM;
      f4 o;
      o.x = xr[p.x]; o.y = xr[p.y]; o.z = xr[p.z]; o.w = xr[p.w];
      __builtin_nontemporal_store(o, (f4*)(ob + rr * N_ELEM) + v);
    }
  }
}

extern "C" void kernel_launch(void* const* d_in, const int* in_sizes, int n_in,
                              void* d_out, int out_size, void* d_ws, size_t ws_size,
                              hipStream_t stream) {
  const float* x = (const float*)d_in[0];
  float* out = (float*)d_out;

  unsigned* winG = (unsigned*)d_ws;                        // 384*416 = 159744 B
  int* perm = (int*)((char*)d_ws + NCHUNK * WINW * 2);     // 7056*4  =  28224 B

  chunk_kernel<<<NCHUNK, TPB, 0, stream>>>(winG);
  trace_kernel<<<TRACE_BLOCKS, TPB, 0, stream>>>(winG, perm);
  gather_kernel<<<N_ROWS / GR, TPB, 0, stream>>>(x, perm, out);  // 512 blocks
}